// Round 6
// baseline (434.143 us; speedup 1.0000x reference)
//
#include <hip/hip_runtime.h>
#include <math.h>

#define NB   8
#define BC   32
#define WIN  14
#define HH   16
#define BKK  288     // 32*3*3
#define CWW  1152    // 32*6*6
#define NXY  36
#define NBLK 1152    // 8 b x 36 xy x 4 cq
#define BPB  144     // blocks per batch
#define PSTR 9       // psumS stride (8 c + 1 pad)
#define EPSF 1e-10f
#define LOG2E 1.4426950408889634f
#define LN2   0.6931471805599453f
#define L2SQ2PI 1.3257480647361593f  // log2(sqrt(2*pi))

__device__ __forceinline__ float ex2(float x) { return __builtin_amdgcn_exp2f(x); }
__device__ __forceinline__ float lg2(float x) { return __builtin_amdgcn_logf(x); }
__device__ __forceinline__ float rcpf(float x) { return __builtin_amdgcn_rcpf(x); }

__device__ __forceinline__ float red16(float v) {
    v += __shfl_xor(v, 1);
    v += __shfl_xor(v, 2);
    v += __shfl_xor(v, 4);
    v += __shfl_xor(v, 8);
    return v;
}

__device__ __forceinline__ float4 f4mul(float s, float4 b) {
    return make_float4(s * b.x, s * b.y, s * b.z, s * b.w);
}
__device__ __forceinline__ float4 f4fma(float s, float4 b, float4 c) {
    return make_float4(fmaf(s, b.x, c.x), fmaf(s, b.y, c.y),
                       fmaf(s, b.z, c.z), fmaf(s, b.w, c.w));
}

// W[m][c][p][q] -> Wt[m][p][c] (float4 over q); also zero the barrier words.
__global__ __launch_bounds__(256)
void wt_kernel(const float4* __restrict__ W4, float4* __restrict__ Wt4,
               unsigned* __restrict__ bar) {
    if (blockIdx.x == 0) bar[threadIdx.x] = 0u;   // 256 uints = 1024 B
    int o = blockIdx.x * 256 + threadIdx.x;       // 288*4*32 = 36864
    if (o < BKK * 128) {
        int c = o & 31, p = (o >> 5) & 3, m = o >> 7;
        Wt4[o] = W4[(m * 32 + c) * 4 + p];
    }
}

// Per-batch sense barrier: one RMW per block; last arriver stores a release
// flag; others poll the flag with plain agent-scope loads (no RMW ping-pong).
// bar[b*32 + 0] = arrival counter (monotone), bar[b*32 + 16] = release gen.
__device__ __forceinline__ void gridbar(unsigned* bar, int b, unsigned gen) {
    __syncthreads();
    if (threadIdx.x == 0) {
        unsigned* cnt  = bar + b * 32;
        unsigned* flag = bar + b * 32 + 16;
        __threadfence();   // release: rows writes visible before arrival
        unsigned old = __hip_atomic_fetch_add(cnt, 1u, __ATOMIC_ACQ_REL,
                                              __HIP_MEMORY_SCOPE_AGENT);
        if (old == gen * BPB - 1) {
            __hip_atomic_store(flag, gen, __ATOMIC_RELEASE,
                               __HIP_MEMORY_SCOPE_AGENT);
        } else {
            while (__hip_atomic_load(flag, __ATOMIC_RELAXED,
                                     __HIP_MEMORY_SCOPE_AGENT) < gen)
                __builtin_amdgcn_s_sleep(8);
        }
        __threadfence();   // acquire: other blocks' rows writes visible
    }
    __syncthreads();
}

// stats phase: thread (c_l 0..7, mch 0..31) covers 1 n x 9 m, full V[16] per m.
// red overlays psumS (synced). Epilogue on tid<128: thread = (h, cc).
template<int STAGE, bool FINAL>
__device__ __forceinline__ void stats_phase(
    const float4* __restrict__ WtB, const float4* poseS4, const float* psumS,
    const float* actS, const float* AIS, float* red, float* mKC, float* aS,
    const float* __restrict__ beta_v, const float* __restrict__ beta_a,
    float lamv, int tid, int c_l, int mch, int cq, int xy, int b,
    float* __restrict__ out)
{
    float ap_n = 0.0f;
    if constexpr (STAGE >= 1) ap_n = aS[c_l];

    float  sum_R = 0.0f;
    float4 sRV[4]  = {make_float4(0,0,0,0), make_float4(0,0,0,0), make_float4(0,0,0,0), make_float4(0,0,0,0)};
    float4 sRV2[4] = {make_float4(0,0,0,0), make_float4(0,0,0,0), make_float4(0,0,0,0), make_float4(0,0,0,0)};

    const int m0 = mch * 9;
    #pragma unroll 3
    for (int i = 0; i < 9; ++i) {
        const int m = m0 + i;
        float4 w0 = WtB[m * 128 +  0];
        float4 w1 = WtB[m * 128 + 32];
        float4 w2 = WtB[m * 128 + 64];
        float4 w3 = WtB[m * 128 + 96];
        float4 P0 = poseS4[m * 4 + 0];
        float4 P1 = poseS4[m * 4 + 1];
        float4 P2 = poseS4[m * 4 + 2];
        float4 P3 = poseS4[m * 4 + 3];
        float4 V0 = f4fma(w0.w, P3, f4fma(w0.z, P2, f4fma(w0.y, P1, f4mul(w0.x, P0))));
        float4 V1 = f4fma(w1.w, P3, f4fma(w1.z, P2, f4fma(w1.y, P1, f4mul(w1.x, P0))));
        float4 V2 = f4fma(w2.w, P3, f4fma(w2.z, P2, f4fma(w2.y, P1, f4mul(w2.x, P0))));
        float4 V3 = f4fma(w3.w, P3, f4fma(w3.z, P2, f4fma(w3.y, P1, f4mul(w3.x, P0))));
        float Ra;
        if constexpr (STAGE == 0) {
            Ra = AIS[m];
        } else {
            float ps = psumS[m * PSTR + c_l];
            Ra = fmaf(ap_n * ps, AIS[m], EPSF * actS[m]);
        }
        sum_R += Ra;
        sRV[0] = f4fma(Ra, V0, sRV[0]);
        sRV[1] = f4fma(Ra, V1, sRV[1]);
        sRV[2] = f4fma(Ra, V2, sRV[2]);
        sRV[3] = f4fma(Ra, V3, sRV[3]);
        sRV2[0] = f4fma(Ra, make_float4(V0.x*V0.x, V0.y*V0.y, V0.z*V0.z, V0.w*V0.w), sRV2[0]);
        sRV2[1] = f4fma(Ra, make_float4(V1.x*V1.x, V1.y*V1.y, V1.z*V1.z, V1.w*V1.w), sRV2[1]);
        sRV2[2] = f4fma(Ra, make_float4(V2.x*V2.x, V2.y*V2.y, V2.z*V2.z, V2.w*V2.w), sRV2[2]);
        sRV2[3] = f4fma(Ra, make_float4(V3.x*V3.x, V3.y*V3.y, V3.z*V3.z, V3.w*V3.w), sRV2[3]);
    }

    // combine the 8 mch within each wave (lane bits 3,4,5)
    float* f1 = reinterpret_cast<float*>(sRV);
    float* f2 = reinterpret_cast<float*>(sRV2);
    #pragma unroll
    for (int k = 0; k < 16; ++k) { f1[k] += __shfl_xor(f1[k], 8); f2[k] += __shfl_xor(f2[k], 8); }
    sum_R += __shfl_xor(sum_R, 8);
    #pragma unroll
    for (int k = 0; k < 16; ++k) { f1[k] += __shfl_xor(f1[k], 16); f2[k] += __shfl_xor(f2[k], 16); }
    sum_R += __shfl_xor(sum_R, 16);
    #pragma unroll
    for (int k = 0; k < 16; ++k) { f1[k] += __shfl_xor(f1[k], 32); f2[k] += __shfl_xor(f2[k], 32); }
    sum_R += __shfl_xor(sum_R, 32);

    __syncthreads();     // all psumS reads done before red overlays it
    if ((tid & 56) == 0) {
        int wv = tid >> 6;                         // 0..3
        float* dst = red + (wv * 8 + c_l) * 33;
        dst[0] = sum_R;
        #pragma unroll
        for (int k = 0; k < 16; ++k) { dst[1 + k] = f1[k]; dst[17 + k] = f2[k]; }
    }
    __syncthreads();

    // epilogue: tid<128, thread = (h = tid&15, cc = tid>>4 in 0..7)
    if (tid < 128) {
        const int h  = tid & 15;
        const int cc = tid >> 4;
        float sR = 0.f, sV = 0.f, sV2 = 0.f;
        #pragma unroll
        for (int j = 0; j < 4; ++j) {
            const float* rr = red + (j * 8 + cc) * 33;
            sR  += rr[0];
            sV  += rr[1 + h];
            sV2 += rr[17 + h];
        }
        float inv = 1.0f / sR;
        float mu  = sV * inv;
        float sig = fmaxf(fmaf(-mu, mu, sV2 * inv), 1e-30f);
        float l2s = lg2(sqrtf(sig) + EPSF);
        float lsum = red16(l2s) * LN2;
        int   cg   = cq * 8 + cc;
        float cost = sR * fmaf(16.0f, beta_v[cg], lsum);
        float z    = lamv * (beta_a[cg] - cost);
        float av   = rcpf(1.0f + ex2(-z * LOG2E));

        if constexpr (!FINAL) {
            mKC[0 * 128 + h * 8 + cc] = mu;
            mKC[1 * 128 + h * 8 + cc] = (-0.5f * LOG2E) / sig;
            mKC[2 * 128 + h * 8 + cc] = -(l2s + L2SQ2PI);
            if (h == 0) aS[cc] = av;
        } else {
            int nn = cg * NXY + xy;
            out[(b * CWW + nn) * HH + h] = mu;
            if (h == 0) out[NB * CWW * HH + b * CWW + nn] = av;
        }
    }
    __syncthreads();
}

// pv phase: mu/K/C register-resident (broadcast LDS reads);
// writes psumS[m][c] in LDS + per-block row partials to global rows.
__device__ __forceinline__ void pv_phase(
    const float4* __restrict__ WtB, const float4* poseS4, float* psumS,
    const float* mKC, const float* aS, float* __restrict__ rows,
    int bid, int c_l, int mch)
{
    float M[16], Kk[16], Cc[16];
    #pragma unroll
    for (int h2 = 0; h2 < 16; ++h2) {
        M[h2]  = mKC[      h2 * 8 + c_l];
        Kk[h2] = mKC[128 + h2 * 8 + c_l];
        Cc[h2] = mKC[256 + h2 * 8 + c_l];
    }
    const float ap = aS[c_l];

    const int m0 = mch * 9;
    #pragma unroll 3
    for (int i = 0; i < 9; ++i) {
        const int m = m0 + i;
        float4 w0 = WtB[m * 128 +  0];
        float4 w1 = WtB[m * 128 + 32];
        float4 w2 = WtB[m * 128 + 64];
        float4 w3 = WtB[m * 128 + 96];
        float4 P0 = poseS4[m * 4 + 0];
        float4 P1 = poseS4[m * 4 + 1];
        float4 P2 = poseS4[m * 4 + 2];
        float4 P3 = poseS4[m * 4 + 3];
        float4 V0 = f4fma(w0.w, P3, f4fma(w0.z, P2, f4fma(w0.y, P1, f4mul(w0.x, P0))));
        float4 V1 = f4fma(w1.w, P3, f4fma(w1.z, P2, f4fma(w1.y, P1, f4mul(w1.x, P0))));
        float4 V2 = f4fma(w2.w, P3, f4fma(w2.z, P2, f4fma(w2.y, P1, f4mul(w2.x, P0))));
        float4 V3 = f4fma(w3.w, P3, f4fma(w3.z, P2, f4fma(w3.y, P1, f4mul(w3.x, P0))));

        float psv = 0.0f;
        float t;
        t = V0.x - M[0];  psv += ex2(fmaf(t * t, Kk[0],  Cc[0]));
        t = V0.y - M[1];  psv += ex2(fmaf(t * t, Kk[1],  Cc[1]));
        t = V0.z - M[2];  psv += ex2(fmaf(t * t, Kk[2],  Cc[2]));
        t = V0.w - M[3];  psv += ex2(fmaf(t * t, Kk[3],  Cc[3]));
        t = V1.x - M[4];  psv += ex2(fmaf(t * t, Kk[4],  Cc[4]));
        t = V1.y - M[5];  psv += ex2(fmaf(t * t, Kk[5],  Cc[5]));
        t = V1.z - M[6];  psv += ex2(fmaf(t * t, Kk[6],  Cc[6]));
        t = V1.w - M[7];  psv += ex2(fmaf(t * t, Kk[7],  Cc[7]));
        t = V2.x - M[8];  psv += ex2(fmaf(t * t, Kk[8],  Cc[8]));
        t = V2.y - M[9];  psv += ex2(fmaf(t * t, Kk[9],  Cc[9]));
        t = V2.z - M[10]; psv += ex2(fmaf(t * t, Kk[10], Cc[10]));
        t = V2.w - M[11]; psv += ex2(fmaf(t * t, Kk[11], Cc[11]));
        t = V3.x - M[12]; psv += ex2(fmaf(t * t, Kk[12], Cc[12]));
        t = V3.y - M[13]; psv += ex2(fmaf(t * t, Kk[13], Cc[13]));
        t = V3.z - M[14]; psv += ex2(fmaf(t * t, Kk[14], Cc[14]));
        t = V3.w - M[15]; psv += ex2(fmaf(t * t, Kk[15], Cc[15]));

        psumS[m * PSTR + c_l] = psv;

        float rv = ap * psv;
        rv += __shfl_xor(rv, 1);
        rv += __shfl_xor(rv, 2);
        rv += __shfl_xor(rv, 4);
        if (c_l == 0) rows[bid * BKK + m] = rv;
    }
}

__device__ __forceinline__ void rowred_phase(
    const float* __restrict__ rows, const float* actS, float* AIS, int b, int tid)
{
    for (int m = tid; m < BKK; m += 256) {
        float s = EPSF;
        const float* rp = rows + b * BPB * BKK + m;
        #pragma unroll 8
        for (int j = 0; j < BPB; ++j) s += rp[j * BKK];
        AIS[m] = actS[m] / s;
    }
    __syncthreads();
}

__global__ __launch_bounds__(256, 5)
void fused_kernel(const float* __restrict__ poses,
                  const float* __restrict__ act,
                  const float4* __restrict__ Wt4,
                  const float* __restrict__ beta_v,
                  const float* __restrict__ beta_a,
                  const float* __restrict__ lam,
                  float* __restrict__ rows0,
                  float* __restrict__ rows1,
                  unsigned* __restrict__ bar,
                  float* __restrict__ out)
{
    __shared__ float4 poseS4[BKK * 4];     // 18432 B
    __shared__ float  psumS[BKK * PSTR];   // 10368 B (red overlays 4*8*33 floats)
    __shared__ float  actS[BKK];           // 1152 B
    __shared__ float  AIS[BKK];            // 1152 B
    __shared__ float  mKC[3 * 128];        // 1536 B  [comp][h][cc]
    __shared__ float  aS[8];               // 32 B
    // total 32672 B -> 5 blocks/CU (5*32768 = 160 KiB exactly); 1152 <= 1280

    const int bid = blockIdx.x;            // b*144 + xy*4 + cq
    const int b   = bid / BPB;
    const int rem = bid % BPB;
    const int xy  = rem >> 2;
    const int cq  = rem & 3;
    const int X = xy / 6, Y = xy % 6;

    const int tid = threadIdx.x;
    const int c_l = tid & 7;               // c within block
    const int mch = tid >> 3;              // 0..31
    const int c   = cq * 8 + c_l;

    // stage pose patch + activations (once for all 5 phases)
    const float4* poses4 = reinterpret_cast<const float4*>(poses);
    for (int idx = tid; idx < BKK * 4; idx += 256) {
        int m = idx >> 2, q = idx & 3;
        int B = m / 9, uv = m % 9, u = uv / 3, v = uv % 3;
        poseS4[idx] = poses4[((b * BC + B) * 196 + (2 * Y + u) * WIN + (2 * X + v)) * 4 + q];
    }
    for (int m = tid; m < BKK; m += 256) {
        int B = m / 9, uv = m % 9, u = uv / 3, v = uv % 3;
        float am = act[(b * BC + B) * 196 + (2 * Y + u) * WIN + (2 * X + v)];
        actS[m] = am;
        AIS[m]  = am * (1.0f / 32.0f);
    }
    __syncthreads();

    const float4* WtB = Wt4 + c;
    const float lamv = lam[0];

    // iter 0
    stats_phase<0, false>(WtB, poseS4, psumS, actS, AIS, psumS, mKC, aS,
                          beta_v, beta_a, lamv, tid, c_l, mch, cq, xy, b, out);
    // iter 1
    pv_phase(WtB, poseS4, psumS, mKC, aS, rows0, bid, c_l, mch);
    gridbar(bar, b, 1u);
    rowred_phase(rows0, actS, AIS, b, tid);
    stats_phase<1, false>(WtB, poseS4, psumS, actS, AIS, psumS, mKC, aS,
                          beta_v, beta_a, lamv, tid, c_l, mch, cq, xy, b, out);
    // iter 2 (final)
    pv_phase(WtB, poseS4, psumS, mKC, aS, rows1, bid, c_l, mch);
    gridbar(bar, b, 2u);
    rowred_phase(rows1, actS, AIS, b, tid);
    stats_phase<1, true>(WtB, poseS4, psumS, actS, AIS, psumS, mKC, aS,
                         beta_v, beta_a, lamv, tid, c_l, mch, cq, xy, b, out);
}

extern "C" void kernel_launch(void* const* d_in, const int* in_sizes, int n_in,
                              void* d_out, int out_size, void* d_ws, size_t ws_size,
                              hipStream_t stream) {
    const float* poses  = (const float*)d_in[0];
    const float* act    = (const float*)d_in[1];
    const float* W      = (const float*)d_in[2];
    const float* beta_v = (const float*)d_in[3];
    const float* beta_a = (const float*)d_in[4];
    const float* lam    = (const float*)d_in[5];
    float* out = (float*)d_out;
    float* ws  = (float*)d_ws;

    unsigned* bar = (unsigned*)ws;                       // 256 uints = 1024 B
    float* Wt    = ws + 256;                             // 147456 floats
    float* rows0 = Wt + BKK * 128 * 4;                   // 1152*288 = 331776
    float* rows1 = rows0 + NBLK * BKK;                   // 331776

    wt_kernel<<<dim3(144), dim3(256), 0, stream>>>((const float4*)W, (float4*)Wt, bar);
    fused_kernel<<<dim3(NBLK), dim3(256), 0, stream>>>(
        poses, act, (const float4*)Wt, beta_v, beta_a, lam,
        rows0, rows1, bar, out);
}

// Round 7
// 413.030 us; speedup vs baseline: 1.0511x; 1.0511x over previous
//
#include <hip/hip_runtime.h>
#include <math.h>

#define NB   8
#define BC   32
#define WIN  14
#define HH   16
#define BKK  288     // 32*3*3
#define CWW  1152    // 32*6*6
#define NXY  36
#define NBLK 1152    // 8 b x 36 xy x 4 cq
#define BPB  144     // blocks per batch
#define PSTR 9       // psumS stride (8 c + 1 pad)
#define EPSF 1e-10f
#define LOG2E 1.4426950408889634f
#define LN2   0.6931471805599453f
#define L2SQ2PI 1.3257480647361593f  // log2(sqrt(2*pi))

__device__ __forceinline__ float ex2(float x) { return __builtin_amdgcn_exp2f(x); }
__device__ __forceinline__ float lg2(float x) { return __builtin_amdgcn_logf(x); }
__device__ __forceinline__ float rcpf(float x) { return __builtin_amdgcn_rcpf(x); }

__device__ __forceinline__ float red16(float v) {
    v += __shfl_xor(v, 1);
    v += __shfl_xor(v, 2);
    v += __shfl_xor(v, 4);
    v += __shfl_xor(v, 8);
    return v;
}

__device__ __forceinline__ float4 f4mul(float s, float4 b) {
    return make_float4(s * b.x, s * b.y, s * b.z, s * b.w);
}
__device__ __forceinline__ float4 f4fma(float s, float4 b, float4 c) {
    return make_float4(fmaf(s, b.x, c.x), fmaf(s, b.y, c.y),
                       fmaf(s, b.z, c.z), fmaf(s, b.w, c.w));
}

// W[m][c][p][q] -> Wt[m][p][c] (float4 over q); also zero the barrier words.
__global__ __launch_bounds__(256)
void wt_kernel(const float4* __restrict__ W4, float4* __restrict__ Wt4,
               unsigned* __restrict__ bar) {
    if (blockIdx.x == 0) bar[threadIdx.x] = 0u;   // 256 uints = 1024 B
    int o = blockIdx.x * 256 + threadIdx.x;       // 288*4*32 = 36864
    if (o < BKK * 128) {
        int c = o & 31, p = (o >> 5) & 3, m = o >> 7;
        Wt4[o] = W4[(m * 32 + c) * 4 + p];
    }
}

// Per-batch sense barrier: one RMW per block; last arriver stores a release
// flag; others poll with plain agent-scope loads (no RMW ping-pong).
__device__ __forceinline__ void gridbar(unsigned* bar, int b, unsigned gen) {
    __syncthreads();
    if (threadIdx.x == 0) {
        unsigned* cnt  = bar + b * 32;
        unsigned* flag = bar + b * 32 + 16;
        __threadfence();
        unsigned old = __hip_atomic_fetch_add(cnt, 1u, __ATOMIC_ACQ_REL,
                                              __HIP_MEMORY_SCOPE_AGENT);
        if (old == gen * BPB - 1) {
            __hip_atomic_store(flag, gen, __ATOMIC_RELEASE,
                               __HIP_MEMORY_SCOPE_AGENT);
        } else {
            while (__hip_atomic_load(flag, __ATOMIC_RELAXED,
                                     __HIP_MEMORY_SCOPE_AGENT) < gen)
                __builtin_amdgcn_s_sleep(8);
        }
        __threadfence();
    }
    __syncthreads();
}

// stats phase: thread (c_l 0..7, hh 0..1, mch 0..15) covers 1 n x 8 h x 18 m.
// Pose is q-major in LDS (conflict-free across mch groups).
template<int STAGE, bool FINAL>
__device__ __forceinline__ void stats_phase(
    const float4* __restrict__ WtB, const float4* poseQ, const float* psumS,
    const float* actS, const float* AIS, float* red, float* mKC, float* aS,
    const float* __restrict__ beta_v, const float* __restrict__ beta_a,
    float lamv, int tid, int c_l, int hh, int mch, int cq, int xy, int b,
    float* __restrict__ out)
{
    float ap_n = 0.0f;
    if constexpr (STAGE >= 1) ap_n = aS[c_l];

    float  sum_R = 0.0f;
    float4 sRV[2]  = {make_float4(0,0,0,0), make_float4(0,0,0,0)};
    float4 sRV2[2] = {make_float4(0,0,0,0), make_float4(0,0,0,0)};

    const int m0   = mch * 18;
    const int wofs = hh * 64;          // p = 2hh, 2hh+1 (each p: +32 float4)
    #pragma unroll 3
    for (int i = 0; i < 18; ++i) {
        const int m = m0 + i;
        float4 wa = WtB[m * 128 + wofs];
        float4 wb = WtB[m * 128 + wofs + 32];
        float4 P0 = poseQ[m];
        float4 P1 = poseQ[288 + m];
        float4 P2 = poseQ[576 + m];
        float4 P3 = poseQ[864 + m];
        float4 V0 = f4fma(wa.w, P3, f4fma(wa.z, P2, f4fma(wa.y, P1, f4mul(wa.x, P0))));
        float4 V1 = f4fma(wb.w, P3, f4fma(wb.z, P2, f4fma(wb.y, P1, f4mul(wb.x, P0))));
        float Ra;
        if constexpr (STAGE == 0) {
            Ra = AIS[m];
        } else {
            float ps = psumS[m * PSTR + c_l];
            Ra = fmaf(ap_n * ps, AIS[m], EPSF * actS[m]);
        }
        sum_R += Ra;
        sRV[0] = f4fma(Ra, V0, sRV[0]);
        sRV[1] = f4fma(Ra, V1, sRV[1]);
        sRV2[0] = f4fma(Ra, make_float4(V0.x*V0.x, V0.y*V0.y, V0.z*V0.z, V0.w*V0.w), sRV2[0]);
        sRV2[1] = f4fma(Ra, make_float4(V1.x*V1.x, V1.y*V1.y, V1.z*V1.z, V1.w*V1.w), sRV2[1]);
    }

    // combine the 4 mch groups within each wave (lane bits 4,5)
    float* f1 = reinterpret_cast<float*>(sRV);
    float* f2 = reinterpret_cast<float*>(sRV2);
    #pragma unroll
    for (int k = 0; k < 8; ++k) { f1[k] += __shfl_xor(f1[k], 16); f2[k] += __shfl_xor(f2[k], 16); }
    sum_R += __shfl_xor(sum_R, 16);
    #pragma unroll
    for (int k = 0; k < 8; ++k) { f1[k] += __shfl_xor(f1[k], 32); f2[k] += __shfl_xor(f2[k], 32); }
    sum_R += __shfl_xor(sum_R, 32);

    __syncthreads();     // all psumS reads done before red overlays it
    if ((tid & 48) == 0) {             // lanes 0..15 of each wave: (c_l, hh)
        int wv = tid >> 6;             // 0..3
        float* dst = red + ((wv * 2 + hh) * 8 + c_l) * 17;
        dst[0] = sum_R;
        #pragma unroll
        for (int k = 0; k < 8; ++k) { dst[1 + k] = f1[k]; dst[9 + k] = f2[k]; }
    }
    __syncthreads();

    // epilogue: tid<128, thread = (h = tid&15, cc = tid>>4 in 0..7)
    if (tid < 128) {
        const int h   = tid & 15;
        const int cc  = tid >> 4;
        const int hhi = h >> 3, hl = h & 7;
        float sR = 0.f, sV = 0.f, sV2 = 0.f;
        #pragma unroll
        for (int j = 0; j < 4; ++j) {
            sR += red[((j * 2) * 8 + cc) * 17];           // hh=0 rows only
            const float* rr = red + ((j * 2 + hhi) * 8 + cc) * 17;
            sV  += rr[1 + hl];
            sV2 += rr[9 + hl];
        }
        float inv = 1.0f / sR;
        float mu  = sV * inv;
        float sig = fmaxf(fmaf(-mu, mu, sV2 * inv), 1e-30f);
        float l2s = lg2(sqrtf(sig) + EPSF);
        float lsum = red16(l2s) * LN2;
        int   cg   = cq * 8 + cc;
        float cost = sR * fmaf(16.0f, beta_v[cg], lsum);
        float z    = lamv * (beta_a[cg] - cost);
        float av   = rcpf(1.0f + ex2(-z * LOG2E));

        if constexpr (!FINAL) {
            mKC[0 * 128 + h * 8 + cc] = mu;
            mKC[1 * 128 + h * 8 + cc] = (-0.5f * LOG2E) / sig;
            mKC[2 * 128 + h * 8 + cc] = -(l2s + L2SQ2PI);
            if (h == 0) aS[cc] = av;
        } else {
            int nn = cg * NXY + xy;
            out[(b * CWW + nn) * HH + h] = mu;
            if (h == 0) out[NB * CWW * HH + b * CWW + nn] = av;
        }
    }
    __syncthreads();
}

// pv phase: 8 h per thread, mu/K/C register-resident (24 regs);
// psum combined across the hh pair via shfl_xor(…,8).
__device__ __forceinline__ void pv_phase(
    const float4* __restrict__ WtB, const float4* poseQ, float* psumS,
    const float* mKC, const float* aS, float* __restrict__ rows,
    int bid, int tid, int c_l, int hh, int mch)
{
    float M[8], Kk[8], Cc[8];
    #pragma unroll
    for (int k = 0; k < 8; ++k) {
        int h = hh * 8 + k;
        M[k]  = mKC[      h * 8 + c_l];
        Kk[k] = mKC[128 + h * 8 + c_l];
        Cc[k] = mKC[256 + h * 8 + c_l];
    }
    const float ap = aS[c_l];

    const int m0   = mch * 18;
    const int wofs = hh * 64;
    #pragma unroll 3
    for (int i = 0; i < 18; ++i) {
        const int m = m0 + i;
        float4 wa = WtB[m * 128 + wofs];
        float4 wb = WtB[m * 128 + wofs + 32];
        float4 P0 = poseQ[m];
        float4 P1 = poseQ[288 + m];
        float4 P2 = poseQ[576 + m];
        float4 P3 = poseQ[864 + m];
        float4 V0 = f4fma(wa.w, P3, f4fma(wa.z, P2, f4fma(wa.y, P1, f4mul(wa.x, P0))));
        float4 V1 = f4fma(wb.w, P3, f4fma(wb.z, P2, f4fma(wb.y, P1, f4mul(wb.x, P0))));

        float psv = 0.0f, t;
        t = V0.x - M[0]; psv += ex2(fmaf(t * t, Kk[0], Cc[0]));
        t = V0.y - M[1]; psv += ex2(fmaf(t * t, Kk[1], Cc[1]));
        t = V0.z - M[2]; psv += ex2(fmaf(t * t, Kk[2], Cc[2]));
        t = V0.w - M[3]; psv += ex2(fmaf(t * t, Kk[3], Cc[3]));
        t = V1.x - M[4]; psv += ex2(fmaf(t * t, Kk[4], Cc[4]));
        t = V1.y - M[5]; psv += ex2(fmaf(t * t, Kk[5], Cc[5]));
        t = V1.z - M[6]; psv += ex2(fmaf(t * t, Kk[6], Cc[6]));
        t = V1.w - M[7]; psv += ex2(fmaf(t * t, Kk[7], Cc[7]));

        psv += __shfl_xor(psv, 8);       // combine h-halves
        psumS[m * PSTR + c_l] = psv;     // both hh lanes write same value

        float rv = ap * psv;
        rv += __shfl_xor(rv, 1);
        rv += __shfl_xor(rv, 2);
        rv += __shfl_xor(rv, 4);
        if ((tid & 15) == 0) rows[bid * BKK + m] = rv;
    }
}

__device__ __forceinline__ void rowred_phase(
    const float* __restrict__ rows, const float* actS, float* AIS, int b, int tid)
{
    for (int m = tid; m < BKK; m += 256) {
        float s = EPSF;
        const float* rp = rows + b * BPB * BKK + m;
        #pragma unroll 8
        for (int j = 0; j < BPB; ++j) s += rp[j * BKK];
        AIS[m] = actS[m] / s;
    }
    __syncthreads();
}

__global__ __launch_bounds__(256, 5)
void fused_kernel(const float* __restrict__ poses,
                  const float* __restrict__ act,
                  const float4* __restrict__ Wt4,
                  const float* __restrict__ beta_v,
                  const float* __restrict__ beta_a,
                  const float* __restrict__ lam,
                  float* __restrict__ rows0,
                  float* __restrict__ rows1,
                  unsigned* __restrict__ bar,
                  float* __restrict__ out)
{
    __shared__ float4 poseQ[BKK * 4];      // 18432 B, q-major: [q][m]
    __shared__ float  psumS[BKK * PSTR];   // 10368 B (red overlays 4*2*8*17=1088 f)
    __shared__ float  actS[BKK];           // 1152 B
    __shared__ float  AIS[BKK];            // 1152 B
    __shared__ float  mKC[3 * 128];        // 1536 B  [comp][h][cc]
    __shared__ float  aS[8];               // 32 B
    // total 32672 B -> 5 blocks/CU (163360 <= 163840); 1152 <= 1280 resident

    const int bid = blockIdx.x;            // b*144 + xy*4 + cq
    const int b   = bid / BPB;
    const int rem = bid % BPB;
    const int xy  = rem >> 2;
    const int cq  = rem & 3;
    const int X = xy / 6, Y = xy % 6;

    const int tid = threadIdx.x;
    const int c_l = tid & 7;
    const int hh  = (tid >> 3) & 1;
    const int mch = tid >> 4;              // 0..15
    const int c   = cq * 8 + c_l;

    // stage pose patch (q-major) + activations, once for all 5 phases
    const float4* poses4 = reinterpret_cast<const float4*>(poses);
    for (int idx = tid; idx < BKK * 4; idx += 256) {
        int m = idx >> 2, q = idx & 3;
        int B = m / 9, uv = m % 9, u = uv / 3, v = uv % 3;
        poseQ[q * BKK + m] =
            poses4[((b * BC + B) * 196 + (2 * Y + u) * WIN + (2 * X + v)) * 4 + q];
    }
    for (int m = tid; m < BKK; m += 256) {
        int B = m / 9, uv = m % 9, u = uv / 3, v = uv % 3;
        float am = act[(b * BC + B) * 196 + (2 * Y + u) * WIN + (2 * X + v)];
        actS[m] = am;
        AIS[m]  = am * (1.0f / 32.0f);
    }
    __syncthreads();

    const float4* WtB = Wt4 + c;
    const float lamv = lam[0];

    // iter 0
    stats_phase<0, false>(WtB, poseQ, psumS, actS, AIS, psumS, mKC, aS,
                          beta_v, beta_a, lamv, tid, c_l, hh, mch, cq, xy, b, out);
    // iter 1
    pv_phase(WtB, poseQ, psumS, mKC, aS, rows0, bid, tid, c_l, hh, mch);
    gridbar(bar, b, 1u);
    rowred_phase(rows0, actS, AIS, b, tid);
    stats_phase<1, false>(WtB, poseQ, psumS, actS, AIS, psumS, mKC, aS,
                          beta_v, beta_a, lamv, tid, c_l, hh, mch, cq, xy, b, out);
    // iter 2 (final)
    pv_phase(WtB, poseQ, psumS, mKC, aS, rows1, bid, tid, c_l, hh, mch);
    gridbar(bar, b, 2u);
    rowred_phase(rows1, actS, AIS, b, tid);
    stats_phase<1, true>(WtB, poseQ, psumS, actS, AIS, psumS, mKC, aS,
                         beta_v, beta_a, lamv, tid, c_l, hh, mch, cq, xy, b, out);
}

extern "C" void kernel_launch(void* const* d_in, const int* in_sizes, int n_in,
                              void* d_out, int out_size, void* d_ws, size_t ws_size,
                              hipStream_t stream) {
    const float* poses  = (const float*)d_in[0];
    const float* act    = (const float*)d_in[1];
    const float* W      = (const float*)d_in[2];
    const float* beta_v = (const float*)d_in[3];
    const float* beta_a = (const float*)d_in[4];
    const float* lam    = (const float*)d_in[5];
    float* out = (float*)d_out;
    float* ws  = (float*)d_ws;

    unsigned* bar = (unsigned*)ws;                       // 256 uints = 1024 B
    float* Wt    = ws + 256;                             // 147456 floats
    float* rows0 = Wt + BKK * 128 * 4;                   // 1152*288 = 331776
    float* rows1 = rows0 + NBLK * BKK;                   // 331776

    wt_kernel<<<dim3(144), dim3(256), 0, stream>>>((const float4*)W, (float4*)Wt, bar);
    fused_kernel<<<dim3(NBLK), dim3(256), 0, stream>>>(
        poses, act, (const float4*)Wt, beta_v, beta_a, lam,
        rows0, rows1, bar, out);
}

// Round 8
// 186.791 us; speedup vs baseline: 2.3242x; 2.2112x over previous
//
#include <hip/hip_runtime.h>
#include <math.h>

#define NB   8
#define BC   32
#define WIN  14
#define HH   16
#define BKK  288     // 32*3*3
#define CWW  1152    // 32*6*6
#define NXY  36
#define GRID 576     // 8 b x 36 xy x 2 chalf
#define BPB  72      // blocks per batch
#define PSTR 17      // psumS stride (16 c + 1 pad)
#define PSF  4896    // 288*17 floats per block psum slab
#define PSF4 1224    // PSF/4
#define EPSF 1e-10f
#define LOG2E 1.4426950408889634f
#define LN2   0.6931471805599453f
#define L2SQ2PI 1.3257480647361593f  // log2(sqrt(2*pi))

__device__ __forceinline__ float ex2(float x) { return __builtin_amdgcn_exp2f(x); }
__device__ __forceinline__ float lg2(float x) { return __builtin_amdgcn_logf(x); }
__device__ __forceinline__ float rcpf(float x) { return __builtin_amdgcn_rcpf(x); }

__device__ __forceinline__ float red16(float v) {
    v += __shfl_xor(v, 1);
    v += __shfl_xor(v, 2);
    v += __shfl_xor(v, 4);
    v += __shfl_xor(v, 8);
    return v;
}

__device__ __forceinline__ float4 f4mul(float s, float4 b) {
    return make_float4(s * b.x, s * b.y, s * b.z, s * b.w);
}
__device__ __forceinline__ float4 f4fma(float s, float4 b, float4 c) {
    return make_float4(fmaf(s, b.x, c.x), fmaf(s, b.y, c.y),
                       fmaf(s, b.z, c.z), fmaf(s, b.w, c.w));
}

// W[m][c][p][q] -> Wt[m][p][c] (float4 over q): c-contiguous compute loads.
__global__ __launch_bounds__(256)
void wt_kernel(const float4* __restrict__ W4, float4* __restrict__ Wt4) {
    int o = blockIdx.x * 256 + threadIdx.x;       // 288*4*32 = 36864
    if (o < BKK * 128) {
        int c = o & 31, p = (o >> 5) & 3, m = o >> 7;
        Wt4[o] = W4[(m * 32 + c) * 4 + p];
    }
}

// ---- shared phase bodies (512 threads: c_l = tid&15, mch = tid>>4 in 0..31,
// each thread: 1 n x 9 m x 16 h). Pose q-major in LDS (conflict-free). ----

template<int STAGE, bool FINAL>
__device__ __forceinline__ void stats_phase(
    const float4* __restrict__ WtB, const float4* poseQ, const float* psumS,
    const float* actS, const float* AIS, float* red, float* mKC, float* aS,
    const float* __restrict__ beta_v, const float* __restrict__ beta_a,
    float lamv, int tid, int c_l, int mch, int chalf, int xy, int b,
    float* __restrict__ out, float* __restrict__ a_g)
{
    float ap_n = 0.0f;
    if constexpr (STAGE >= 1) ap_n = aS[c_l];

    float  sum_R = 0.0f;
    float4 sRV[4]  = {make_float4(0,0,0,0), make_float4(0,0,0,0), make_float4(0,0,0,0), make_float4(0,0,0,0)};
    float4 sRV2[4] = {make_float4(0,0,0,0), make_float4(0,0,0,0), make_float4(0,0,0,0), make_float4(0,0,0,0)};

    const int m0 = mch * 9;
    #pragma unroll 3
    for (int i = 0; i < 9; ++i) {
        const int m = m0 + i;
        float4 w0 = WtB[m * 128 +  0];
        float4 w1 = WtB[m * 128 + 32];
        float4 w2 = WtB[m * 128 + 64];
        float4 w3 = WtB[m * 128 + 96];
        float4 P0 = poseQ[m];
        float4 P1 = poseQ[288 + m];
        float4 P2 = poseQ[576 + m];
        float4 P3 = poseQ[864 + m];
        float4 V0 = f4fma(w0.w, P3, f4fma(w0.z, P2, f4fma(w0.y, P1, f4mul(w0.x, P0))));
        float4 V1 = f4fma(w1.w, P3, f4fma(w1.z, P2, f4fma(w1.y, P1, f4mul(w1.x, P0))));
        float4 V2 = f4fma(w2.w, P3, f4fma(w2.z, P2, f4fma(w2.y, P1, f4mul(w2.x, P0))));
        float4 V3 = f4fma(w3.w, P3, f4fma(w3.z, P2, f4fma(w3.y, P1, f4mul(w3.x, P0))));
        float Ra;
        if constexpr (STAGE == 0) {
            Ra = AIS[m];
        } else {
            float ps = psumS[m * PSTR + c_l];
            Ra = fmaf(ap_n * ps, AIS[m], EPSF * actS[m]);
        }
        sum_R += Ra;
        sRV[0] = f4fma(Ra, V0, sRV[0]);
        sRV[1] = f4fma(Ra, V1, sRV[1]);
        sRV[2] = f4fma(Ra, V2, sRV[2]);
        sRV[3] = f4fma(Ra, V3, sRV[3]);
        sRV2[0] = f4fma(Ra, make_float4(V0.x*V0.x, V0.y*V0.y, V0.z*V0.z, V0.w*V0.w), sRV2[0]);
        sRV2[1] = f4fma(Ra, make_float4(V1.x*V1.x, V1.y*V1.y, V1.z*V1.z, V1.w*V1.w), sRV2[1]);
        sRV2[2] = f4fma(Ra, make_float4(V2.x*V2.x, V2.y*V2.y, V2.z*V2.z, V2.w*V2.w), sRV2[2]);
        sRV2[3] = f4fma(Ra, make_float4(V3.x*V3.x, V3.y*V3.y, V3.z*V3.z, V3.w*V3.w), sRV2[3]);
    }

    // combine the 4 mch groups within each wave (lane bits 4,5)
    float* f1 = reinterpret_cast<float*>(sRV);
    float* f2 = reinterpret_cast<float*>(sRV2);
    #pragma unroll
    for (int k = 0; k < 16; ++k) { f1[k] += __shfl_xor(f1[k], 16); f2[k] += __shfl_xor(f2[k], 16); }
    sum_R += __shfl_xor(sum_R, 16);
    #pragma unroll
    for (int k = 0; k < 16; ++k) { f1[k] += __shfl_xor(f1[k], 32); f2[k] += __shfl_xor(f2[k], 32); }
    sum_R += __shfl_xor(sum_R, 32);

    __syncthreads();     // all psumS reads done before red overlays it
    if ((tid & 48) == 0) {
        int wv = tid >> 6;                       // 0..7
        float* dst = red + (wv * 16 + c_l) * 33;
        dst[0] = sum_R;
        #pragma unroll
        for (int k = 0; k < 16; ++k) { dst[1 + k] = f1[k]; dst[17 + k] = f2[k]; }
    }
    __syncthreads();

    // epilogue: tid<256, thread = (h = tid&15, cc = tid>>4 in 0..15)
    if (tid < 256) {
        const int h  = tid & 15;
        const int cc = tid >> 4;
        float sR = 0.f, sV = 0.f, sV2 = 0.f;
        #pragma unroll
        for (int j = 0; j < 8; ++j) {
            const float* rr = red + (j * 16 + cc) * 33;
            sR  += rr[0];
            sV  += rr[1 + h];
            sV2 += rr[17 + h];
        }
        float inv = 1.0f / sR;
        float mu  = sV * inv;
        float sig = fmaxf(fmaf(-mu, mu, sV2 * inv), 1e-30f);
        float l2s = lg2(sqrtf(sig) + EPSF);
        float lsum = red16(l2s) * LN2;
        int   cg   = chalf * 16 + cc;
        float cost = sR * fmaf(16.0f, beta_v[cg], lsum);
        float z    = lamv * (beta_a[cg] - cost);
        float av   = rcpf(1.0f + ex2(-z * LOG2E));

        if constexpr (!FINAL) {
            mKC[0 * 256 + h * 16 + cc] = mu;
            mKC[1 * 256 + h * 16 + cc] = (-0.5f * LOG2E) / sig;
            mKC[2 * 256 + h * 16 + cc] = -(l2s + L2SQ2PI);
            if (h == 0) {
                aS[cc] = av;
                a_g[(b * NXY + xy) * 32 + cg] = av;   // for the next kernel
            }
        } else {
            int nn = cg * NXY + xy;
            out[(b * CWW + nn) * HH + h] = mu;
            if (h == 0) out[NB * CWW * HH + b * CWW + nn] = av;
        }
    }
    __syncthreads();
}

__device__ __forceinline__ void pv_phase(
    const float4* __restrict__ WtB, const float4* poseQ, float* psumS,
    const float* mKC, const float* aS, float* __restrict__ rows,
    int bid, int tid, int c_l, int mch)
{
    float M[16], Kk[16], Cc[16];
    #pragma unroll
    for (int k = 0; k < 16; ++k) {
        M[k]  = mKC[      k * 16 + c_l];
        Kk[k] = mKC[256 + k * 16 + c_l];
        Cc[k] = mKC[512 + k * 16 + c_l];
    }
    const float ap = aS[c_l];

    const int m0 = mch * 9;
    #pragma unroll 3
    for (int i = 0; i < 9; ++i) {
        const int m = m0 + i;
        float4 w0 = WtB[m * 128 +  0];
        float4 w1 = WtB[m * 128 + 32];
        float4 w2 = WtB[m * 128 + 64];
        float4 w3 = WtB[m * 128 + 96];
        float4 P0 = poseQ[m];
        float4 P1 = poseQ[288 + m];
        float4 P2 = poseQ[576 + m];
        float4 P3 = poseQ[864 + m];
        float4 V0 = f4fma(w0.w, P3, f4fma(w0.z, P2, f4fma(w0.y, P1, f4mul(w0.x, P0))));
        float4 V1 = f4fma(w1.w, P3, f4fma(w1.z, P2, f4fma(w1.y, P1, f4mul(w1.x, P0))));
        float4 V2 = f4fma(w2.w, P3, f4fma(w2.z, P2, f4fma(w2.y, P1, f4mul(w2.x, P0))));
        float4 V3 = f4fma(w3.w, P3, f4fma(w3.z, P2, f4fma(w3.y, P1, f4mul(w3.x, P0))));

        float psv = 0.0f, t;
        t = V0.x - M[0];  psv += ex2(fmaf(t * t, Kk[0],  Cc[0]));
        t = V0.y - M[1];  psv += ex2(fmaf(t * t, Kk[1],  Cc[1]));
        t = V0.z - M[2];  psv += ex2(fmaf(t * t, Kk[2],  Cc[2]));
        t = V0.w - M[3];  psv += ex2(fmaf(t * t, Kk[3],  Cc[3]));
        t = V1.x - M[4];  psv += ex2(fmaf(t * t, Kk[4],  Cc[4]));
        t = V1.y - M[5];  psv += ex2(fmaf(t * t, Kk[5],  Cc[5]));
        t = V1.z - M[6];  psv += ex2(fmaf(t * t, Kk[6],  Cc[6]));
        t = V1.w - M[7];  psv += ex2(fmaf(t * t, Kk[7],  Cc[7]));
        t = V2.x - M[8];  psv += ex2(fmaf(t * t, Kk[8],  Cc[8]));
        t = V2.y - M[9];  psv += ex2(fmaf(t * t, Kk[9],  Cc[9]));
        t = V2.z - M[10]; psv += ex2(fmaf(t * t, Kk[10], Cc[10]));
        t = V2.w - M[11]; psv += ex2(fmaf(t * t, Kk[11], Cc[11]));
        t = V3.x - M[12]; psv += ex2(fmaf(t * t, Kk[12], Cc[12]));
        t = V3.y - M[13]; psv += ex2(fmaf(t * t, Kk[13], Cc[13]));
        t = V3.z - M[14]; psv += ex2(fmaf(t * t, Kk[14], Cc[14]));
        t = V3.w - M[15]; psv += ex2(fmaf(t * t, Kk[15], Cc[15]));

        psumS[m * PSTR + c_l] = psv;

        float rv = ap * psv;
        rv += __shfl_xor(rv, 1);
        rv += __shfl_xor(rv, 2);
        rv += __shfl_xor(rv, 4);
        rv += __shfl_xor(rv, 8);
        if (c_l == 0) rows[bid * BKK + m] = rv;
    }
}

__device__ __forceinline__ void stage_patch(
    const float* __restrict__ poses, const float* __restrict__ act,
    int b, int X, int Y, int tid, float4* poseQ, float* actS)
{
    const float4* poses4 = reinterpret_cast<const float4*>(poses);
    for (int idx = tid; idx < BKK * 4; idx += 512) {
        int m = idx >> 2, q = idx & 3;
        int B = m / 9, uv = m % 9, u = uv / 3, v = uv % 3;
        poseQ[q * BKK + m] =
            poses4[((b * BC + B) * 196 + (2 * Y + u) * WIN + (2 * X + v)) * 4 + q];
    }
    for (int m = tid; m < BKK; m += 512) {
        int B = m / 9, uv = m % 9, u = uv / 3, v = uv % 3;
        actS[m] = act[(b * BC + B) * 196 + (2 * Y + u) * WIN + (2 * X + v)];
    }
}

__device__ __forceinline__ void rowred_phase(
    const float* __restrict__ rows, const float* actS, float* AIS, int b, int tid)
{
    for (int m = tid; m < BKK; m += 512) {
        float s = EPSF;
        const float* rp = rows + b * BPB * BKK + m;
        #pragma unroll 8
        for (int j = 0; j < BPB; ++j) s += rp[j * BKK];
        AIS[m] = actS[m] / s;
    }
}

// ---- kernels ----

// K1: stats0 (R = 1/32) -> mu/K/C in LDS -> pv1 -> psum/rows0/a to global
__global__ __launch_bounds__(512)
void k1_kernel(const float* __restrict__ poses, const float* __restrict__ act,
               const float4* __restrict__ Wt4,
               const float* __restrict__ beta_v, const float* __restrict__ beta_a,
               const float* __restrict__ lam,
               float4* __restrict__ psum_g, float* __restrict__ rows0,
               float* __restrict__ a_g)
{
    __shared__ float4 poseQ[BKK * 4];
    __shared__ float  psumS[PSF];          // red overlays (8*16*33 = 4224 <= 4896)
    __shared__ float  actS[BKK];
    __shared__ float  AIS[BKK];
    __shared__ float  mKC[3 * 256];
    __shared__ float  aS[16];

    const int bid = blockIdx.x;
    const int chalf = bid & 1;
    const int xy  = (bid >> 1) % NXY;
    const int b   = bid / BPB;
    const int X = xy / 6, Y = xy % 6;
    const int tid = threadIdx.x;
    const int c_l = tid & 15;
    const int mch = tid >> 4;
    const int c   = chalf * 16 + c_l;

    stage_patch(poses, act, b, X, Y, tid, poseQ, actS);
    for (int m = tid; m < BKK; m += 512) AIS[m] = actS[m] * (1.0f / 32.0f);
    __syncthreads();

    const float4* WtB = Wt4 + c;
    const float lamv = lam[0];

    stats_phase<0, false>(WtB, poseQ, psumS, actS, AIS, psumS, mKC, aS,
                          beta_v, beta_a, lamv, tid, c_l, mch, chalf, xy, b,
                          nullptr, a_g);
    pv_phase(WtB, poseQ, psumS, mKC, aS, rows0, bid, tid, c_l, mch);
    __syncthreads();
    const float4* ps4 = reinterpret_cast<const float4*>(psumS);
    for (int i = tid; i < PSF4; i += 512) psum_g[bid * PSF4 + i] = ps4[i];
}

// K2: rowred(rows0) + stats1 + pv2 -> psum/rows1/a updated in place
__global__ __launch_bounds__(512)
void k2_kernel(const float* __restrict__ poses, const float* __restrict__ act,
               const float4* __restrict__ Wt4,
               const float* __restrict__ beta_v, const float* __restrict__ beta_a,
               const float* __restrict__ lam,
               float4* __restrict__ psum_g, const float* __restrict__ rows0,
               float* __restrict__ rows1, float* __restrict__ a_g)
{
    __shared__ float4 poseQ[BKK * 4];
    __shared__ float  psumS[PSF];
    __shared__ float  actS[BKK];
    __shared__ float  AIS[BKK];
    __shared__ float  mKC[3 * 256];
    __shared__ float  aS[16];

    const int bid = blockIdx.x;
    const int chalf = bid & 1;
    const int xy  = (bid >> 1) % NXY;
    const int b   = bid / BPB;
    const int X = xy / 6, Y = xy % 6;
    const int tid = threadIdx.x;
    const int c_l = tid & 15;
    const int mch = tid >> 4;
    const int c   = chalf * 16 + c_l;

    stage_patch(poses, act, b, X, Y, tid, poseQ, actS);
    float4* ps4w = reinterpret_cast<float4*>(psumS);
    for (int i = tid; i < PSF4; i += 512) ps4w[i] = psum_g[bid * PSF4 + i];
    if (tid < 16) aS[tid] = a_g[(b * NXY + xy) * 32 + chalf * 16 + tid];
    __syncthreads();
    rowred_phase(rows0, actS, AIS, b, tid);
    __syncthreads();

    const float4* WtB = Wt4 + c;
    const float lamv = lam[0];

    stats_phase<1, false>(WtB, poseQ, psumS, actS, AIS, psumS, mKC, aS,
                          beta_v, beta_a, lamv, tid, c_l, mch, chalf, xy, b,
                          nullptr, a_g);
    pv_phase(WtB, poseQ, psumS, mKC, aS, rows1, bid, tid, c_l, mch);
    __syncthreads();
    const float4* ps4 = reinterpret_cast<const float4*>(psumS);
    for (int i = tid; i < PSF4; i += 512) psum_g[bid * PSF4 + i] = ps4[i];
}

// K3: rowred(rows1) + stats2 (final) -> out
__global__ __launch_bounds__(512)
void k3_kernel(const float* __restrict__ poses, const float* __restrict__ act,
               const float4* __restrict__ Wt4,
               const float* __restrict__ beta_v, const float* __restrict__ beta_a,
               const float* __restrict__ lam,
               const float4* __restrict__ psum_g, const float* __restrict__ rows1,
               const float* __restrict__ a_g, float* __restrict__ out)
{
    __shared__ float4 poseQ[BKK * 4];
    __shared__ float  psumS[PSF];
    __shared__ float  actS[BKK];
    __shared__ float  AIS[BKK];
    __shared__ float  mKC[3 * 256];
    __shared__ float  aS[16];

    const int bid = blockIdx.x;
    const int chalf = bid & 1;
    const int xy  = (bid >> 1) % NXY;
    const int b   = bid / BPB;
    const int X = xy / 6, Y = xy % 6;
    const int tid = threadIdx.x;
    const int c_l = tid & 15;
    const int mch = tid >> 4;
    const int c   = chalf * 16 + c_l;

    stage_patch(poses, act, b, X, Y, tid, poseQ, actS);
    float4* ps4w = reinterpret_cast<float4*>(psumS);
    for (int i = tid; i < PSF4; i += 512) ps4w[i] = psum_g[bid * PSF4 + i];
    if (tid < 16) aS[tid] = a_g[(b * NXY + xy) * 32 + chalf * 16 + tid];
    __syncthreads();
    rowred_phase(rows1, actS, AIS, b, tid);
    __syncthreads();

    const float4* WtB = Wt4 + c;
    const float lamv = lam[0];

    stats_phase<1, true>(WtB, poseQ, psumS, actS, AIS, psumS, mKC, aS,
                         beta_v, beta_a, lamv, tid, c_l, mch, chalf, xy, b,
                         out, nullptr);
}

extern "C" void kernel_launch(void* const* d_in, const int* in_sizes, int n_in,
                              void* d_out, int out_size, void* d_ws, size_t ws_size,
                              hipStream_t stream) {
    const float* poses  = (const float*)d_in[0];
    const float* act    = (const float*)d_in[1];
    const float* W      = (const float*)d_in[2];
    const float* beta_v = (const float*)d_in[3];
    const float* beta_a = (const float*)d_in[4];
    const float* lam    = (const float*)d_in[5];
    float* out = (float*)d_out;
    float* ws  = (float*)d_ws;

    float* Wt     = ws;                          // 147456 floats
    float* rows0  = Wt + BKK * 128 * 4;          // 576*288 = 165888
    float* rows1  = rows0 + GRID * BKK;          // 165888
    float* psum_g = rows1 + GRID * BKK;          // 576*4896 = 2,820,096
    float* a_g    = psum_g + GRID * PSF;         // 9216
    // total ~13.2 MB

    const float4* Wt4 = (const float4*)Wt;

    wt_kernel<<<dim3(144), dim3(256), 0, stream>>>((const float4*)W, (float4*)Wt);
    k1_kernel<<<dim3(GRID), dim3(512), 0, stream>>>(
        poses, act, Wt4, beta_v, beta_a, lam, (float4*)psum_g, rows0, a_g);
    k2_kernel<<<dim3(GRID), dim3(512), 0, stream>>>(
        poses, act, Wt4, beta_v, beta_a, lam, (float4*)psum_g, rows0, rows1, a_g);
    k3_kernel<<<dim3(GRID), dim3(512), 0, stream>>>(
        poses, act, Wt4, beta_v, beta_a, lam, (const float4*)psum_g, rows1, a_g, out);
}